// Round 10
// baseline (184.684 us; speedup 1.0000x reference)
//
#include <hip/hip_runtime.h>
#include <math.h>

#define VIF_EPS       1e-10f
#define SIGMA_NSQ     2.0f
#define SIGMA_MAX_INV (4.0f / (255.0f * 255.0f))
#define GAIN_LIMIT    100.0f

typedef float v2f __attribute__((ext_vector_type(2)));
typedef float v4f __attribute__((ext_vector_type(4)));

static __device__ __forceinline__ v2f splat2(float s) {
    v2f v; v.x = s; v.y = s; return v;
}

// jnp.pad mode='reflect' (no edge duplication). Overshoot < dim, single reflection suffices.
__device__ __forceinline__ int reflect_idx(int i, int n) {
    i = (i < 0) ? -i : i;
    i = (i >= n) ? (2 * n - 2 - i) : i;
    return i;
}

// Reference: sigma=N/5; g=exp(-x^2/(2 sigma^2)); win=outer(g,g)/sum -> separable gn = g/sum(g).
// R9: computed once into workspace (same device float ops -> bit-identical weights).
template <int N>
__device__ __forceinline__ void fill_weights_global(float* gw) {
    const float sigma = (float)N / 5.0f;
    const float denom = 2.0f * sigma * sigma;
    float tmp[N];
    float s = 0.0f;
    for (int i = 0; i < N; ++i) {
        float x = (float)i - (float)(N - 1) * 0.5f;
        float g = expf(-(x * x) / denom);
        tmp[i] = g;
        s += g;
    }
    for (int i = 0; i < N; ++i) gw[i] = tmp[i] / s;
}

__global__ __launch_bounds__(64) void init_weights_kernel(float* __restrict__ gw) {
    const int tid = threadIdx.x;
    if (tid == 0) fill_weights_global<17>(gw + 0);
    else if (tid == 1) fill_weights_global<9>(gw + 17);
    else if (tid == 2) fill_weights_global<5>(gw + 26);
    else if (tid == 3) fill_weights_global<3>(gw + 31);
}

// Weight buffer offsets per N.
__host__ __device__ constexpr int w_off(int N) {
    return (N == 17) ? 0 : (N == 9) ? 17 : (N == 5) ? 26 : 31;
}

// R7: 256-column tile (VC = blockDim = 256). Output tile width (multiple of 4).
// 1920 = 8*240 exact at level 0.
constexpr int tile_w(int N) { return (256 - (N - 1)) & ~3; }

// ---- static shared layouts ----
// R14: 5 ROW-SLOTS (25600 B) instead of 8 rows (40960 B) -> 6 blocks/CU by LDS
// (163840/25600 = 6.4; was exactly 4). Phase-2 tasks 0..255 only touch rows 0..4
// and tasks 256.. only rows 4..7 (XG4 in 60..63 for all N), so the tile is
// consumed in two halves with rows 5-7 written into recycled slots 0-2.
template <int N>
struct alignas(16) StatsSmem {
    v2f   a[5][256];    // (conv r, conv d)           10240 B
    v2f   bq[5][256];   // (conv r^2, conv d^2)       10240 B
    float c[5][256];    // conv rd                     5120 B
};                      // total 25600 B
// Down: vertical (r,d)-packed results for a 120x8 output tile (16128 B).
template <int N>
struct alignas(16) DownSmem {
    v2f vb[8][252];
};

// ---------------- stats body (vertical-first separable VIF) ----------------
// bx flattened Y-MAJOR (ytile = bx % sy) for L2 reuse of vertical halos.
// R6: channel-pair packed fp32. R7: 1 column/thread phase 1; halo-minimum rows;
// u32 voffset + SGPR-base loads. R9: weights from global. R13: burst row loads.
// R14: split-phase LDS (5 slots). Thread tid still processes tasks {tid, tid+256}
// in that order -> per-thread sums, reduction tree, and all conv values
// bit-identical to the 8-row version.
template <int N>
__device__ __forceinline__ void stats_body(
    StatsSmem<N>& sm, const float* __restrict__ refp, const float* __restrict__ distp,
    const float* __restrict__ gw,
    int h, int w, float shift, double2* __restrict__ partial,
    int sy, int sx, int bx, int b) {
    constexpr int P   = (N - 1) / 2;
    constexpr int TW  = tile_w(N);
    constexpr int TH  = 8;
    constexpr int LR  = TH + 2 * P;      // rows loaded per column (halo minimum)
    constexpr int XG4 = TW / 4;          // 4-output x-groups per row (60..63)
    constexpr int NT  = TH * XG4;        // phase-2 tasks (480..504)
    static_assert(5 * XG4 >= 256, "phase 2a tasks must fit rows 0..4");

    const int tid = threadIdx.x;
    const int ytile = bx % sy;
    const int xtile = bx / sy;
    const int x0 = xtile * TW;
    const int y0 = ytile * TH;

    float wr[N];
#pragma unroll
    for (int j = 0; j < N; ++j) wr[j] = gw[j];   // uniform -> s_load, stays SGPR

    // ---- Phase 1: vertical conv from global (1 column/thread, 8 outputs) ----
    v2f accA[TH], accB[TH];
    float accC[TH];
    {
        const int cc = tid;                       // column 0..255
        const int gx = reflect_idx(x0 + cc - P, w);
        const float* rbase = refp  + (size_t)b * h * w;   // uniform -> SGPR base
        const float* dbase = distp + (size_t)b * h * w;

        // R13: burst load (interior: shared u32 voffset walk; boundary: reflected).
        float rrow[LR], drow[LR];
        const int rowlo = y0 - P;
        if (rowlo >= 0 && rowlo + LR <= h) {
            unsigned voff = (unsigned)(rowlo * w + gx) * 4u;
            const unsigned vstep = (unsigned)w * 4u;
#pragma unroll
            for (int i = 0; i < LR; ++i) {
                rrow[i] = *(const float*)((const char*)rbase + voff);
                drow[i] = *(const float*)((const char*)dbase + voff);
                voff += vstep;
            }
        } else {
#pragma unroll
            for (int i = 0; i < LR; ++i) {
                const int gy = reflect_idx(rowlo + i, h);
                const size_t o = (size_t)gy * w + gx;
                rrow[i] = rbase[o];
                drow[i] = dbase[o];
            }
        }

#pragma unroll
        for (int t = 0; t < TH; ++t) {
            accA[t] = splat2(0.f);
            accB[t] = splat2(0.f);
            accC[t] = 0.f;
        }
#pragma unroll
        for (int i = 0; i < LR; ++i) {
            const float r = rrow[i] - shift;
            const float d = drow[i] - shift;
            v2f rd; rd.x = r; rd.y = d;
            v2f sq = rd * rd;          // v_pk_mul_f32: (r^2, d^2)
            const float x = r * d;
#pragma unroll
            for (int t = 0; t < TH; ++t) {
                const int j = i - t;               // j-ascending per output t
                if (j >= 0 && j < N) {
                    const float wj = wr[j];
                    accA[t] += splat2(wj) * rd;    // v_pk_fma_f32
                    accB[t] += splat2(wj) * sq;
                    accC[t] += wj * x;
                }
            }
        }
        // R14: write rows 0..4 only; rows 5..7 stay in registers through phase 2a.
#pragma unroll
        for (int t = 0; t < 5; ++t) {
            sm.a[t][tid]  = accA[t];   // ds_write_b64, compile-time row offsets
            sm.bq[t][tid] = accB[t];
            sm.c[t][tid]  = accC[t];
        }
    }
    __syncthreads();

    // ---- Phase 2: horizontal conv + VIF math (4 outputs/task, 2 half-phases) ----
    float num_v = 0.f, den_v = 0.f;
    constexpr int WC  = N + 3;         // window columns (even: N odd)
    constexpr int F4C = (WC + 3) / 4;

    auto do_task = [&](int task, int slot) {
        const int row = task / XG4;          // true output row (for gy)
        const int xg  = task - row * XG4;

        v2f muA[4], muB[4];
        float muC[4];
#pragma unroll
        for (int q = 0; q < 4; ++q) {
            muA[q] = splat2(0.f);
            muB[q] = splat2(0.f);
            muC[q] = 0.f;
        }

        const v4f* A4 = (const v4f*)&sm.a[slot][xg * 4];
        const v4f* B4 = (const v4f*)&sm.bq[slot][xg * 4];
#pragma unroll
        for (int f = 0; f < WC / 2; ++f) {
            v4f ta = A4[f];
            v4f tb = B4[f];
#pragma unroll
            for (int hlf = 0; hlf < 2; ++hlf) {
                const int k = 2 * f + hlf;
                v2f pa = hlf ? __builtin_shufflevector(ta, ta, 2, 3)
                             : __builtin_shufflevector(ta, ta, 0, 1);
                v2f pb = hlf ? __builtin_shufflevector(tb, tb, 2, 3)
                             : __builtin_shufflevector(tb, tb, 0, 1);
#pragma unroll
                for (int q = 0; q < 4; ++q) {
                    const int j = k - q;  // j-ascending per output
                    if (j >= 0 && j < N) {
                        const float wj = wr[j];
                        muA[q] += splat2(wj) * pa;
                        muB[q] += splat2(wj) * pb;
                    }
                }
            }
        }
        // Scalar rd plane.
        {
            const v4f* C4 = (const v4f*)&sm.c[slot][xg * 4];
#pragma unroll
            for (int f = 0; f < F4C; ++f) {
                v4f t = C4[f];
#pragma unroll
                for (int e = 0; e < 4; ++e) {
                    const int k = 4 * f + e;
                    const float x = (e == 0) ? t.x : (e == 1) ? t.y
                                  : (e == 2) ? t.z : t.w;
#pragma unroll
                    for (int q = 0; q < 4; ++q) {
                        const int j = k - q;
                        if (j >= 0 && j < N) muC[q] += wr[j] * x;
                    }
                }
            }
        }

        const int gy = y0 + row;
#pragma unroll
        for (int q = 0; q < 4; ++q) {
            int gx = x0 + xg * 4 + q;
            if (gx < w && gy < h) {
                float mu1 = muA[q].x, mu2 = muA[q].y;
                float s1  = fmaxf(0.f, muB[q].x - mu1 * mu1);
                float s2  = fmaxf(0.f, muB[q].y - mu2 * mu2);
                float s12 = muC[q] - mu1 * mu2;

                float g  = s12 / (s1 + VIF_EPS);
                float sv = s2 - g * s12;
                if (s1 < VIF_EPS) { g = 0.f; sv = s2; s1 = 0.f; }
                if (s2 < VIF_EPS) { g = 0.f; sv = 0.f; }
                if (g  < 0.f)     { sv = s2; g = 0.f; }
                if (sv <= VIF_EPS) sv = VIF_EPS;
                g = fminf(g, GAIN_LIMIT);

                float num_ar = __log2f(1.f + g * g * s1 / (sv + SIGMA_NSQ));
                float den_ar = __log2f(1.f + s1 / SIGMA_NSQ);
                if (s12 < 0.f) num_ar = 0.f;
                if (s1 < SIGMA_NSQ) { num_ar = 1.f - s2 * SIGMA_MAX_INV; den_ar = 1.f; }
                num_v += num_ar;
                den_v += den_ar;
            }
        }
    };

    // Phase 2a: task = tid (rows 0..4, slot == row). Same task set as old rep 0.
    {
        const int task = tid;
        do_task(task, task / XG4);
    }
    __syncthreads();                      // all phase-2a reads complete

    // Phase 1b: rows 5..7 into recycled slots 0..2 (row 4 stays in slot 4).
#pragma unroll
    for (int t = 5; t < TH; ++t) {
        sm.a[t - 5][tid]  = accA[t];
        sm.bq[t - 5][tid] = accB[t];
        sm.c[t - 5][tid]  = accC[t];
    }
    __syncthreads();

    // Phase 2b: task = tid + 256 (rows 4..7). Same task set as old rep 1.
    {
        const int task = tid + 256;
        if (task < NT) {
            const int row = task / XG4;
            do_task(task, (row == 4) ? 4 : (row - 5));
        }
    }

    // Block reduction. rsum overlaid on the a-plane.
#pragma unroll
    for (int off = 32; off > 0; off >>= 1) {
        num_v += __shfl_down(num_v, off);
        den_v += __shfl_down(den_v, off);
    }
    __syncthreads();                      // phase-2b LDS reads complete
    float* rs = reinterpret_cast<float*>(&sm);
    const int wid = tid >> 6, lane = tid & 63;
    if (lane == 0) { rs[wid] = num_v; rs[4 + wid] = den_v; }
    __syncthreads();
    if (tid == 0) {
        float ns = rs[0] + rs[1] + rs[2] + rs[3];
        float ds = rs[4] + rs[5] + rs[6] + rs[7];
        partial[(size_t)b * (sy * sx) + bx] = make_double2((double)ns, (double)ds);
    }
}

// ---------------- downsample body: vertical-first, 120x8 output tile ----------------
template <int N>
__device__ __forceinline__ void down_body(
    DownSmem<N>& sm, const float* __restrict__ rin, const float* __restrict__ din,
    const float* __restrict__ gw,
    float* __restrict__ rout, float* __restrict__ dout,
    int h, int w, int h2, int w2, float shift, int dgx, int bx, int b) {
    constexpr int P   = (N - 1) / 2;
    constexpr int TOW = 120, TOH = 8;
    constexpr int IC  = 2 * (TOW - 1) + N;   // input cols needed (<= 247)
    constexpr int NR  = 2 * (TOH - 1) + N;   // input rows needed (14+N)
    constexpr int XG4 = TOW / 4;             // 30 x-groups (4 outputs each)
    constexpr int WL  = N + 6;               // window v2f cols for 4 outputs

    float wr[N];
#pragma unroll
    for (int j = 0; j < N; ++j) wr[j] = gw[j];   // uniform -> s_load

    const int tid = threadIdx.x;
    const int xt  = bx % dgx;
    const int yt  = bx / dgx;
    const int x0  = xt * TOW;
    const int y0  = yt * TOH;

    // ---- Vertical decimating pass (packed, burst-loaded) ----
    if (tid < IC) {
        const int gx = reflect_idx(2 * x0 - P + tid, w);
        const int rowlo = 2 * y0 - P;
        const float* rbase = rin + (size_t)b * h * w;
        const float* dbase = din + (size_t)b * h * w;

        float rr[NR], dd[NR];
        const bool interior = (rowlo >= 0) && (rowlo + NR <= h);
        if (interior) {
            unsigned voff = (unsigned)(rowlo * w + gx) * 4u;
            const unsigned vstep = (unsigned)w * 4u;
#pragma unroll
            for (int i = 0; i < NR; ++i) {
                rr[i] = *(const float*)((const char*)rbase + voff);
                dd[i] = *(const float*)((const char*)dbase + voff);
                voff += vstep;
            }
        } else {
#pragma unroll
            for (int i = 0; i < NR; ++i) {
                const int gy = reflect_idx(rowlo + i, h);
                const size_t o = (size_t)gy * w + gx;
                rr[i] = rbase[o];
                dd[i] = dbase[o];
            }
        }

        v2f acc[TOH];
#pragma unroll
        for (int t = 0; t < TOH; ++t) acc[t] = splat2(0.f);
#pragma unroll
        for (int i = 0; i < NR; ++i) {
            v2f x; x.x = rr[i] - shift; x.y = dd[i] - shift;
#pragma unroll
            for (int t = 0; t < TOH; ++t) {
                const int j = i - 2 * t;
                if (j >= 0 && j < N) acc[t] += splat2(wr[j]) * x;
            }
        }
#pragma unroll
        for (int t = 0; t < TOH; ++t) sm.vb[t][tid] = acc[t];   // ds_write_b64
    }
    __syncthreads();

    // ---- Horizontal decimating pass (packed) ----
    if (tid < TOH * XG4) {   // 240 threads
        const int row = tid / XG4;
        const int xg  = tid - row * XG4;

        v2f o[4];
#pragma unroll
        for (int q = 0; q < 4; ++q) o[q] = splat2(0.f);

        const v4f* s4 = (const v4f*)&sm.vb[row][8 * xg];
#pragma unroll
        for (int f = 0; f < (WL + 1) / 2; ++f) {
            v4f t = s4[f];
#pragma unroll
            for (int hlf = 0; hlf < 2; ++hlf) {
                const int k = 2 * f + hlf;
                v2f p = hlf ? __builtin_shufflevector(t, t, 2, 3)
                            : __builtin_shufflevector(t, t, 0, 1);
#pragma unroll
                for (int q = 0; q < 4; ++q) {
                    const int j = k - 2 * q;   // j-ascending per output: bit-identical
                    if (j >= 0 && j < N) o[q] += splat2(wr[j]) * p;
                }
            }
        }
        const int gy = y0 + row;
        if (gy < h2) {
            float* rp = rout + (size_t)b * h2 * w2 + (size_t)gy * w2 + x0 + 4 * xg;
            float* dp = dout + (size_t)b * h2 * w2 + (size_t)gy * w2 + x0 + 4 * xg;
            *(float4*)rp = make_float4(o[0].x, o[1].x, o[2].x, o[3].x);
            *(float4*)dp = make_float4(o[0].y, o[1].y, o[2].y, o[3].y);
        }
    }
}

// ---------------- fused kernels (static union LDS; grid split by blockIdx.x) ----------------
template <int NS, int ND>
__global__ __launch_bounds__(256) void fused_kernel(
    const float* __restrict__ sref, const float* __restrict__ sdist,
    const float* __restrict__ gw,
    int sh, int sw, float sshift, double2* __restrict__ partial, int sy, int sx,
    float* __restrict__ drout, float* __restrict__ ddout,
    int dh2, int dw2, int dgx, int nStats) {
    __shared__ union {
        StatsSmem<NS> s;
        DownSmem<ND>  d;
    } u;
    const int bx = blockIdx.x;
    const int b  = blockIdx.z;
    if (bx < nStats)
        stats_body<NS>(u.s, sref, sdist, gw + w_off(NS), sh, sw, sshift,
                       partial, sy, sx, bx, b);
    else
        down_body<ND>(u.d, sref, sdist, gw + w_off(ND), drout, ddout,
                      sh, sw, dh2, dw2, sshift, dgx, bx - nStats, b);
}

template <int N>
__global__ __launch_bounds__(256) void stats_only_kernel(
    const float* __restrict__ refp, const float* __restrict__ distp,
    const float* __restrict__ gw,
    int h, int w, float shift, double2* __restrict__ partial, int sy, int sx) {
    __shared__ StatsSmem<N> sm;
    stats_body<N>(sm, refp, distp, gw + w_off(N), h, w, shift, partial,
                  sy, sx, blockIdx.x, blockIdx.z);
}

// 16 blocks: one per (batch, scale). Sums double2 partials, writes num/den to out.
__global__ __launch_bounds__(256) void reduce_kernel(
    const double2* __restrict__ part, float* __restrict__ out,
    int4 bases, int4 counts) {
    __shared__ double sn[4], sd[4];
    const int s = blockIdx.x & 3;
    const int b = blockIdx.x >> 2;
    const int base = (&bases.x)[s];
    const int cnt  = (&counts.x)[s];
    const double2* p = part + base + (size_t)b * cnt;

    double ns = 0.0, ds = 0.0;
    for (int i = threadIdx.x; i < cnt; i += 256) {
        double2 v = p[i];
        ns += v.x;
        ds += v.y;
    }
#pragma unroll
    for (int off = 32; off > 0; off >>= 1) {
        ns += __shfl_down(ns, off);
        ds += __shfl_down(ds, off);
    }
    const int wid = threadIdx.x >> 6, lane = threadIdx.x & 63;
    if (lane == 0) { sn[wid] = ns; sd[wid] = ds; }
    __syncthreads();
    if (threadIdx.x == 0) {
        double Nv = sn[0] + sn[1] + sn[2] + sn[3];
        double Dv = sd[0] + sd[1] + sd[2] + sd[3];
        out[b * 4 + s] = (float)(Nv / Dv);
    }
}

extern "C" void kernel_launch(void* const* d_in, const int* in_sizes, int n_in,
                              void* d_out, int out_size, void* d_ws, size_t ws_size,
                              hipStream_t stream) {
    const float* ref  = (const float*)d_in[0];
    const float* dist = (const float*)d_in[1];
    float* out = (float*)d_out;

    const int B = 4;
    const int H0 = 1080, W0 = 1920;
    const int H1 = 540,  W1 = 960;
    const int H2 = 270,  W2 = 480;
    const int H3 = 135,  W3 = 240;

    char*  ws  = (char*)d_ws;
    size_t off = 0;
    auto alloc = [&](size_t bytes) -> void* {
        void* p = ws + off;
        off += (bytes + 255) & ~(size_t)255;
        return p;
    };
    float* gw    = (float*)alloc(34 * sizeof(float));   // weight table (17+9+5+3)
    float* ref1  = (float*)alloc((size_t)B * H1 * W1 * 4);
    float* dist1 = (float*)alloc((size_t)B * H1 * W1 * 4);
    float* ref2  = (float*)alloc((size_t)B * H2 * W2 * 4);
    float* dist2 = (float*)alloc((size_t)B * H2 * W2 * 4);
    float* ref3  = (float*)alloc((size_t)B * H3 * W3 * 4);
    float* dist3 = (float*)alloc((size_t)B * H3 * W3 * 4);

    // Stats grids (tile = tile_w(N) x 8), flattened y-major.
    // tile_w: 17->240 (1920 = 8*240 exact), 9->248, 5->252, 3->252.
    const int sx0 = (W0 + tile_w(17) - 1) / tile_w(17), sy0 = (H0 + 7) / 8;
    const int sx1 = (W1 + tile_w(9)  - 1) / tile_w(9),  sy1 = (H1 + 7) / 8;
    const int sx2 = (W2 + tile_w(5)  - 1) / tile_w(5),  sy2 = (H2 + 7) / 8;
    const int sx3 = (W3 + tile_w(3)  - 1) / tile_w(3),  sy3 = (H3 + 7) / 8;
    const int n0 = sx0 * sy0, n1 = sx1 * sy1, n2 = sx2 * sy2, n3 = sx3 * sy3;

    // Down grids: 120x8 output tiles (W1/W2/W3 are exact multiples of 120).
    const int dgx1 = W1 / 120, nD1 = dgx1 * ((H1 + 7) / 8);
    const int dgx2 = W2 / 120, nD2 = dgx2 * ((H2 + 7) / 8);
    const int dgx3 = W3 / 120, nD3 = dgx3 * ((H3 + 7) / 8);

    double2* part = (double2*)alloc((size_t)B * (n0 + n1 + n2 + n3) * sizeof(double2));
    double2* p0 = part;
    double2* p1 = p0 + (size_t)B * n0;
    double2* p2 = p1 + (size_t)B * n1;
    double2* p3 = p2 + (size_t)B * n2;

    dim3 blk(256);

    // K0: weight table (once; bit-identical device float ops).
    init_weights_kernel<<<1, 64, 0, stream>>>(gw);

    // K1: stats<17>(level0) + down<9>(level0 -> level1)
    fused_kernel<17, 9><<<dim3(n0 + nD1, 1, B), blk, 0, stream>>>(
        ref, dist, gw, H0, W0, 128.0f, p0, sy0, sx0,
        ref1, dist1, H1, W1, dgx1, n0);

    // K2: stats<9>(level1) + down<5>(level1 -> level2)
    fused_kernel<9, 5><<<dim3(n1 + nD2, 1, B), blk, 0, stream>>>(
        ref1, dist1, gw, H1, W1, 0.0f, p1, sy1, sx1,
        ref2, dist2, H2, W2, dgx2, n1);

    // K3: stats<5>(level2) + down<3>(level2 -> level3)
    fused_kernel<5, 3><<<dim3(n2 + nD3, 1, B), blk, 0, stream>>>(
        ref2, dist2, gw, H2, W2, 0.0f, p2, sy2, sx2,
        ref3, dist3, H3, W3, dgx3, n2);

    // K4: stats<3>(level3)
    stats_only_kernel<3><<<dim3(n3, 1, B), blk, 0, stream>>>(
        ref3, dist3, gw, H3, W3, 0.0f, p3, sy3, sx3);

    // K5: num/den per (b, scale)
    reduce_kernel<<<16, 256, 0, stream>>>(
        part, out,
        make_int4(0, B * n0, B * (n0 + n1), B * (n0 + n1 + n2)),
        make_int4(n0, n1, n2, n3));
}

// Round 11
// 166.444 us; speedup vs baseline: 1.1096x; 1.1096x over previous
//
#include <hip/hip_runtime.h>
#include <math.h>

#define VIF_EPS       1e-10f
#define SIGMA_NSQ     2.0f
#define SIGMA_MAX_INV (4.0f / (255.0f * 255.0f))
#define GAIN_LIMIT    100.0f

typedef float v2f __attribute__((ext_vector_type(2)));
typedef float v4f __attribute__((ext_vector_type(4)));

static __device__ __forceinline__ v2f splat2(float s) {
    v2f v; v.x = s; v.y = s; return v;
}

// jnp.pad mode='reflect' (no edge duplication). Overshoot < dim, single reflection suffices.
__device__ __forceinline__ int reflect_idx(int i, int n) {
    i = (i < 0) ? -i : i;
    i = (i >= n) ? (2 * n - 2 - i) : i;
    return i;
}

// Reference: sigma=N/5; g=exp(-x^2/(2 sigma^2)); win=outer(g,g)/sum -> separable gn = g/sum(g).
// R9: computed once into workspace (same device float ops -> bit-identical weights).
template <int N>
__device__ __forceinline__ void fill_weights_global(float* gw) {
    const float sigma = (float)N / 5.0f;
    const float denom = 2.0f * sigma * sigma;
    float tmp[N];
    float s = 0.0f;
    for (int i = 0; i < N; ++i) {
        float x = (float)i - (float)(N - 1) * 0.5f;
        float g = expf(-(x * x) / denom);
        tmp[i] = g;
        s += g;
    }
    for (int i = 0; i < N; ++i) gw[i] = tmp[i] / s;
}

__global__ __launch_bounds__(64) void init_weights_kernel(float* __restrict__ gw) {
    const int tid = threadIdx.x;
    if (tid == 0) fill_weights_global<17>(gw + 0);
    else if (tid == 1) fill_weights_global<9>(gw + 17);
    else if (tid == 2) fill_weights_global<5>(gw + 26);
    else if (tid == 3) fill_weights_global<3>(gw + 31);
}

// Weight buffer offsets per N.
__host__ __device__ constexpr int w_off(int N) {
    return (N == 17) ? 0 : (N == 9) ? 17 : (N == 5) ? 26 : 31;
}

// R7: 256-column tile. Output tile width (multiple of 4). 1920 = 8*240 exact.
constexpr int tile_w(int N) { return (256 - (N - 1)) & ~3; }

// ---- static shared layouts ----
// R8: EXACT-FIT 40960 B = 4 blocks/CU in 160 KiB exactly (K1/K2 stats path).
template <int N>
struct alignas(16) StatsSmem {
    v2f   a[8][256];    // (conv r, conv d)           16384 B
    v2f   bq[8][256];   // (conv r^2, conv d^2)       16384 B
    float c[8][256];    // conv rd                     8192 B
};                      // total 40960 B exactly
// Down: vertical (r,d)-packed results for a 120x8 output tile.
template <int N>
struct alignas(16) DownSmem {
    v2f vb[8][252];
};
// R15 (=R12, fence-free this time): stats<3>-from-level2 working set. vb3 overlays
// the planes region (sequential, barrier-separated); patch lives beside it.
// ~60 KB -> only KL23's 340 blocks see this (sub-1-round grid; occupancy moot).
struct alignas(16) Stats3Smem {
    union {
        StatsSmem<3> planes;   // 40960 B (stats phases)
        v2f vb3[10][481];      // 38480 B (build phases A/B)
    } u2;
    v2f patch[10][240];        // 19200 B
};

// ---------------- stats body (vertical-first separable VIF) ----------------
// bx flattened Y-MAJOR (ytile = bx % sy) for L2 reuse of vertical halos.
// R6: channel-pair packed fp32. R7: 1 column/thread phase 1; halo-minimum rows;
// u32 voffset + SGPR-base loads. R8: exact-fit LDS + rsum overlay. R9: weights
// from global. R13: burst row loads. R15: optional FROM_PATCH phase-1 source
// (level3 recomputed in-block; bit-identical values -- proven in R8, absmax 0.0).
template <int N, bool FROM_PATCH>
__device__ __forceinline__ void stats_body(
    StatsSmem<N>& sm, const float* __restrict__ refp, const float* __restrict__ distp,
    const v2f* __restrict__ patch,
    const float* __restrict__ gw,
    int h, int w, float shift, double2* __restrict__ partial,
    int sy, int sx, int bx, int b) {
    constexpr int P   = (N - 1) / 2;
    constexpr int TW  = tile_w(N);
    constexpr int TH  = 8;
    constexpr int LR  = TH + 2 * P;      // rows loaded per column (halo minimum)
    constexpr int XG4 = TW / 4;          // 4-output x-groups per row
    constexpr int NT  = TH * XG4;        // phase-2 tasks (<= 504)
    constexpr int REPS = (NT + 255) / 256;

    const int tid = threadIdx.x;
    const int ytile = bx % sy;
    const int xtile = bx / sy;
    const int x0 = xtile * TW;
    const int y0 = ytile * TH;

    float wr[N];
#pragma unroll
    for (int j = 0; j < N; ++j) wr[j] = gw[j];   // uniform -> s_load, stays SGPR

    // ---- Phase 1: vertical conv (1 column/thread, 8 outputs) ----
    {
        const int cc = tid;                       // column 0..255
        const int gx = reflect_idx(x0 + cc - P, w);

        v2f accA[TH], accB[TH];
        float accC[TH];
#pragma unroll
        for (int t = 0; t < TH; ++t) {
            accA[t] = splat2(0.f);
            accB[t] = splat2(0.f);
            accC[t] = 0.f;
        }

        auto acc_push = [&](int i, float r, float d) {
            v2f rd; rd.x = r; rd.y = d;
            v2f sq = rd * rd;          // v_pk_mul_f32: (r^2, d^2)
            float x = r * d;
#pragma unroll
            for (int t = 0; t < TH; ++t) {
                const int j = i - t;               // j-ascending per output t
                if (j >= 0 && j < N) {
                    const float wj = wr[j];
                    accA[t] += splat2(wj) * rd;    // v_pk_fma_f32
                    accB[t] += splat2(wj) * sq;
                    accC[t] += wj * x;
                }
            }
        };

        if constexpr (FROM_PATCH) {
            // R15: level-3 values recomputed in-block (reflection baked into rows).
#pragma unroll
            for (int i = 0; i < LR; ++i) {
                v2f pv = patch[i * 240 + gx];
                acc_push(i, pv.x, pv.y);
            }
        } else {
            const float* rbase = refp  + (size_t)b * h * w;   // uniform -> SGPR base
            const float* dbase = distp + (size_t)b * h * w;

            // R13: burst load (interior: shared u32 voffset walk; boundary: reflected).
            float rrow[LR], drow[LR];
            const int rowlo = y0 - P;
            if (rowlo >= 0 && rowlo + LR <= h) {
                unsigned voff = (unsigned)(rowlo * w + gx) * 4u;
                const unsigned vstep = (unsigned)w * 4u;
#pragma unroll
                for (int i = 0; i < LR; ++i) {
                    rrow[i] = *(const float*)((const char*)rbase + voff);
                    drow[i] = *(const float*)((const char*)dbase + voff);
                    voff += vstep;
                }
            } else {
#pragma unroll
                for (int i = 0; i < LR; ++i) {
                    const int gy = reflect_idx(rowlo + i, h);
                    const size_t o = (size_t)gy * w + gx;
                    rrow[i] = rbase[o];
                    drow[i] = dbase[o];
                }
            }
#pragma unroll
            for (int i = 0; i < LR; ++i)
                acc_push(i, rrow[i] - shift, drow[i] - shift);
        }
#pragma unroll
        for (int t = 0; t < TH; ++t) {
            sm.a[t][cc]  = accA[t];   // ds_write_b64, compile-time row offsets
            sm.bq[t][cc] = accB[t];
            sm.c[t][cc]  = accC[t];
        }
    }
    __syncthreads();

    // ---- Phase 2: horizontal conv + VIF math (4 outputs/task, REPS task reps) ----
    float num_v = 0.f, den_v = 0.f;
    {
        constexpr int WC  = N + 3;         // window columns (even: N odd)
        constexpr int F4C = (WC + 3) / 4;
#pragma unroll
        for (int rep = 0; rep < REPS; ++rep) {
            const int task = tid + 256 * rep;
            if (task < NT) {
                const int row = task / XG4;
                const int xg  = task - row * XG4;

                v2f muA[4], muB[4];
                float muC[4];
#pragma unroll
                for (int q = 0; q < 4; ++q) {
                    muA[q] = splat2(0.f);
                    muB[q] = splat2(0.f);
                    muC[q] = 0.f;
                }

                const v4f* A4 = (const v4f*)&sm.a[row][xg * 4];
                const v4f* B4 = (const v4f*)&sm.bq[row][xg * 4];
#pragma unroll
                for (int f = 0; f < WC / 2; ++f) {
                    v4f ta = A4[f];
                    v4f tb = B4[f];
#pragma unroll
                    for (int hlf = 0; hlf < 2; ++hlf) {
                        const int k = 2 * f + hlf;
                        v2f pa = hlf ? __builtin_shufflevector(ta, ta, 2, 3)
                                     : __builtin_shufflevector(ta, ta, 0, 1);
                        v2f pb = hlf ? __builtin_shufflevector(tb, tb, 2, 3)
                                     : __builtin_shufflevector(tb, tb, 0, 1);
#pragma unroll
                        for (int q = 0; q < 4; ++q) {
                            const int j = k - q;  // j-ascending per output
                            if (j >= 0 && j < N) {
                                const float wj = wr[j];
                                muA[q] += splat2(wj) * pa;
                                muB[q] += splat2(wj) * pb;
                            }
                        }
                    }
                }
                // Scalar rd plane.
                {
                    const v4f* C4 = (const v4f*)&sm.c[row][xg * 4];
#pragma unroll
                    for (int f = 0; f < F4C; ++f) {
                        v4f t = C4[f];
#pragma unroll
                        for (int e = 0; e < 4; ++e) {
                            const int k = 4 * f + e;
                            const float x = (e == 0) ? t.x : (e == 1) ? t.y
                                          : (e == 2) ? t.z : t.w;
#pragma unroll
                            for (int q = 0; q < 4; ++q) {
                                const int j = k - q;
                                if (j >= 0 && j < N) muC[q] += wr[j] * x;
                            }
                        }
                    }
                }

                const int gy = y0 + row;
#pragma unroll
                for (int q = 0; q < 4; ++q) {
                    int gx = x0 + xg * 4 + q;
                    if (gx < w && gy < h) {
                        float mu1 = muA[q].x, mu2 = muA[q].y;
                        float s1  = fmaxf(0.f, muB[q].x - mu1 * mu1);
                        float s2  = fmaxf(0.f, muB[q].y - mu2 * mu2);
                        float s12 = muC[q] - mu1 * mu2;

                        float g  = s12 / (s1 + VIF_EPS);
                        float sv = s2 - g * s12;
                        if (s1 < VIF_EPS) { g = 0.f; sv = s2; s1 = 0.f; }
                        if (s2 < VIF_EPS) { g = 0.f; sv = 0.f; }
                        if (g  < 0.f)     { sv = s2; g = 0.f; }
                        if (sv <= VIF_EPS) sv = VIF_EPS;
                        g = fminf(g, GAIN_LIMIT);

                        float num_ar = __log2f(1.f + g * g * s1 / (sv + SIGMA_NSQ));
                        float den_ar = __log2f(1.f + s1 / SIGMA_NSQ);
                        if (s12 < 0.f) num_ar = 0.f;
                        if (s1 < SIGMA_NSQ) { num_ar = 1.f - s2 * SIGMA_MAX_INV; den_ar = 1.f; }
                        num_v += num_ar;
                        den_v += den_ar;
                    }
                }
            }
        }
    }

    // Block reduction. rsum overlaid on the a-plane.
#pragma unroll
    for (int off = 32; off > 0; off >>= 1) {
        num_v += __shfl_down(num_v, off);
        den_v += __shfl_down(den_v, off);
    }
    __syncthreads();                      // phase-2 LDS reads complete
    float* rs = reinterpret_cast<float*>(&sm);
    const int wid = tid >> 6, lane = tid & 63;
    if (lane == 0) { rs[wid] = num_v; rs[4 + wid] = den_v; }
    __syncthreads();
    if (tid == 0) {
        float ns = rs[0] + rs[1] + rs[2] + rs[3];
        float ds = rs[4] + rs[5] + rs[6] + rs[7];
        partial[(size_t)b * (sy * sx) + bx] = make_double2((double)ns, (double)ds);
    }
}

// ---------------- downsample body: vertical-first, 120x8 output tile ----------------
// R13: vertical pass burst-loads all NR rows into registers before the tap loop.
template <int N>
__device__ __forceinline__ void down_body(
    DownSmem<N>& sm, const float* __restrict__ rin, const float* __restrict__ din,
    const float* __restrict__ gw,
    float* __restrict__ rout, float* __restrict__ dout,
    int h, int w, int h2, int w2, float shift, int dgx, int bx, int b) {
    constexpr int P   = (N - 1) / 2;
    constexpr int TOW = 120, TOH = 8;
    constexpr int IC  = 2 * (TOW - 1) + N;   // input cols needed (<= 247)
    constexpr int NR  = 2 * (TOH - 1) + N;   // input rows needed (14+N)
    constexpr int XG4 = TOW / 4;             // 30 x-groups (4 outputs each)
    constexpr int WL  = N + 6;               // window v2f cols for 4 outputs

    float wr[N];
#pragma unroll
    for (int j = 0; j < N; ++j) wr[j] = gw[j];   // uniform -> s_load

    const int tid = threadIdx.x;
    const int xt  = bx % dgx;
    const int yt  = bx / dgx;
    const int x0  = xt * TOW;
    const int y0  = yt * TOH;

    // ---- Vertical decimating pass (packed, burst-loaded) ----
    if (tid < IC) {
        const int gx = reflect_idx(2 * x0 - P + tid, w);
        const int rowlo = 2 * y0 - P;
        const float* rbase = rin + (size_t)b * h * w;
        const float* dbase = din + (size_t)b * h * w;

        float rr[NR], dd[NR];
        const bool interior = (rowlo >= 0) && (rowlo + NR <= h);
        if (interior) {
            unsigned voff = (unsigned)(rowlo * w + gx) * 4u;
            const unsigned vstep = (unsigned)w * 4u;
#pragma unroll
            for (int i = 0; i < NR; ++i) {
                rr[i] = *(const float*)((const char*)rbase + voff);
                dd[i] = *(const float*)((const char*)dbase + voff);
                voff += vstep;
            }
        } else {
#pragma unroll
            for (int i = 0; i < NR; ++i) {
                const int gy = reflect_idx(rowlo + i, h);
                const size_t o = (size_t)gy * w + gx;
                rr[i] = rbase[o];
                dd[i] = dbase[o];
            }
        }

        v2f acc[TOH];
#pragma unroll
        for (int t = 0; t < TOH; ++t) acc[t] = splat2(0.f);
#pragma unroll
        for (int i = 0; i < NR; ++i) {
            v2f x; x.x = rr[i] - shift; x.y = dd[i] - shift;
#pragma unroll
            for (int t = 0; t < TOH; ++t) {
                const int j = i - 2 * t;
                if (j >= 0 && j < N) acc[t] += splat2(wr[j]) * x;
            }
        }
#pragma unroll
        for (int t = 0; t < TOH; ++t) sm.vb[t][tid] = acc[t];   // ds_write_b64
    }
    __syncthreads();

    // ---- Horizontal decimating pass (packed) ----
    if (tid < TOH * XG4) {   // 240 threads
        const int row = tid / XG4;
        const int xg  = tid - row * XG4;

        v2f o[4];
#pragma unroll
        for (int q = 0; q < 4; ++q) o[q] = splat2(0.f);

        const v4f* s4 = (const v4f*)&sm.vb[row][8 * xg];
#pragma unroll
        for (int f = 0; f < (WL + 1) / 2; ++f) {
            v4f t = s4[f];
#pragma unroll
            for (int hlf = 0; hlf < 2; ++hlf) {
                const int k = 2 * f + hlf;
                v2f p = hlf ? __builtin_shufflevector(t, t, 2, 3)
                            : __builtin_shufflevector(t, t, 0, 1);
#pragma unroll
                for (int q = 0; q < 4; ++q) {
                    const int j = k - 2 * q;   // j-ascending per output: bit-identical
                    if (j >= 0 && j < N) o[q] += splat2(wr[j]) * p;
                }
            }
        }
        const int gy = y0 + row;
        if (gy < h2) {
            float* rp = rout + (size_t)b * h2 * w2 + (size_t)gy * w2 + x0 + 4 * xg;
            float* dp = dout + (size_t)b * h2 * w2 + (size_t)gy * w2 + x0 + 4 * xg;
            *(float4*)rp = make_float4(o[0].x, o[1].x, o[2].x, o[3].x);
            *(float4*)dp = make_float4(o[0].y, o[1].y, o[2].y, o[3].y);
        }
    }
}

// ---------------- fused kernels K1/K2 (unchanged codegen path) ----------------
template <int NS, int ND>
__global__ __launch_bounds__(256) void fused_kernel(
    const float* __restrict__ sref, const float* __restrict__ sdist,
    const float* __restrict__ gw,
    int sh, int sw, float sshift, double2* __restrict__ partial, int sy, int sx,
    float* __restrict__ drout, float* __restrict__ ddout,
    int dh2, int dw2, int dgx, int nStats) {
    __shared__ union {
        StatsSmem<NS> s;
        DownSmem<ND>  d;
    } u;
    const int bx = blockIdx.x;
    const int b  = blockIdx.z;
    if (bx < nStats)
        stats_body<NS, false>(u.s, sref, sdist, nullptr, gw + w_off(NS), sh, sw,
                              sshift, partial, sy, sx, bx, b);
    else
        down_body<ND>(u.d, sref, sdist, gw + w_off(ND), drout, ddout,
                      sh, sw, dh2, dw2, sshift, dgx, bx - nStats, b);
}

// ---------------- R15: build level-3 patch in LDS from level2 ----------------
// Replicates down<3>'s exact float ops (vertical-first, j-ascending 3-tap,
// per-row/col reflection) -> level3 values bit-identical to the old global
// path. PROVEN: R8 used this verbatim and passed with absmax 0.0.
__device__ __forceinline__ void build_l3_patch(
    v2f* __restrict__ vb3 /*[10][481]*/, v2f* __restrict__ patch /*[10][240]*/,
    const float* __restrict__ r2, const float* __restrict__ d2,
    const float* __restrict__ gw3, int y0, int b) {
    constexpr int H2v = 270, W2v = 480, H3v = 135;
    const int tid = threadIdx.x;
    const float w0 = gw3[0], w1 = gw3[1], w2 = gw3[2];
    const float* rb = r2 + (size_t)b * H2v * W2v;
    const float* db = d2 + (size_t)b * H2v * W2v;

    // Phase A: vertical decimate. t -> level2 col reflect(t-1, 480).
#pragma unroll
    for (int rep = 0; rep < 2; ++rep) {
        const int t = tid + 256 * rep;
        if (t < 481) {
            const int c2 = reflect_idx(t - 1, W2v);
#pragma unroll
            for (int py = 0; py < 10; ++py) {
                const int y3  = reflect_idx(y0 - 1 + py, H3v);   // level3 reflection
                const int r0  = reflect_idx(2 * y3 - 1, H2v);    // level2 reflection
                const int r1  = 2 * y3;
                const int r2i = 2 * y3 + 1;                      // <= 269, in range
                v2f m = splat2(0.f);
                v2f x;
                x.x = rb[(size_t)r0 * W2v + c2];  x.y = db[(size_t)r0 * W2v + c2];
                m += splat2(w0) * x;
                x.x = rb[(size_t)r1 * W2v + c2];  x.y = db[(size_t)r1 * W2v + c2];
                m += splat2(w1) * x;
                x.x = rb[(size_t)r2i * W2v + c2]; x.y = db[(size_t)r2i * W2v + c2];
                m += splat2(w2) * x;
                vb3[py * 481 + t] = m;
            }
        }
    }
    __syncthreads();
    // Phase B: horizontal decimate -> patch[py][x3], tap j uses vb3[2*x3 + j].
#pragma unroll
    for (int rep = 0; rep < 10; ++rep) {
        const int idx = tid + 256 * rep;
        if (idx < 2400) {
            const int py = idx / 240;
            const int x3 = idx - py * 240;
            v2f o = splat2(0.f);
            o += splat2(w0) * vb3[py * 481 + 2 * x3 + 0];
            o += splat2(w1) * vb3[py * 481 + 2 * x3 + 1];
            o += splat2(w2) * vb3[py * 481 + 2 * x3 + 2];
            patch[py * 240 + x3] = o;
        }
    }
    __syncthreads();
}

// ---------------- KL23: stats<5>(level2) ∥ stats<3>(recomputed level3) ----------------
// R15: both halves depend ONLY on level2 -> no internal ordering, NO counter,
// NO __threadfence (R7/R8 lesson: device-scope fences force L2 writebacks,
// ~30-70us). Partials written normally; K5 reduces as before.
__global__ __launch_bounds__(256) void level23_kernel(
    const float* __restrict__ ref2, const float* __restrict__ dist2,
    const float* __restrict__ gw,
    double2* __restrict__ p2, double2* __restrict__ p3) {
    __shared__ union {
        StatsSmem<5> s5;
        Stats3Smem   s3;
    } u;
    const int bx = blockIdx.x;   // 0..84
    const int b  = blockIdx.z;

    if (bx < 68) {
        stats_body<5, false>(u.s5, ref2, dist2, nullptr, gw + w_off(5),
                             270, 480, 0.f, p2, 34, 2, bx, b);
    } else {
        const int bx3 = bx - 68;              // 0..16, sy3=17, sx3=1
        build_l3_patch(&u.s3.u2.vb3[0][0], &u.s3.patch[0][0],
                       ref2, dist2, gw + w_off(3), bx3 * 8, b);
        stats_body<3, true>(u.s3.u2.planes, nullptr, nullptr, &u.s3.patch[0][0],
                            gw + w_off(3), 135, 240, 0.f, p3, 17, 1, bx3, b);
    }
}

// 16 blocks: one per (batch, scale). Sums double2 partials, writes num/den to out.
__global__ __launch_bounds__(256) void reduce_kernel(
    const double2* __restrict__ part, float* __restrict__ out,
    int4 bases, int4 counts) {
    __shared__ double sn[4], sd[4];
    const int s = blockIdx.x & 3;
    const int b = blockIdx.x >> 2;
    const int base = (&bases.x)[s];
    const int cnt  = (&counts.x)[s];
    const double2* p = part + base + (size_t)b * cnt;

    double ns = 0.0, ds = 0.0;
    for (int i = threadIdx.x; i < cnt; i += 256) {
        double2 v = p[i];
        ns += v.x;
        ds += v.y;
    }
#pragma unroll
    for (int off = 32; off > 0; off >>= 1) {
        ns += __shfl_down(ns, off);
        ds += __shfl_down(ds, off);
    }
    const int wid = threadIdx.x >> 6, lane = threadIdx.x & 63;
    if (lane == 0) { sn[wid] = ns; sd[wid] = ds; }
    __syncthreads();
    if (threadIdx.x == 0) {
        double Nv = sn[0] + sn[1] + sn[2] + sn[3];
        double Dv = sd[0] + sd[1] + sd[2] + sd[3];
        out[b * 4 + s] = (float)(Nv / Dv);
    }
}

extern "C" void kernel_launch(void* const* d_in, const int* in_sizes, int n_in,
                              void* d_out, int out_size, void* d_ws, size_t ws_size,
                              hipStream_t stream) {
    const float* ref  = (const float*)d_in[0];
    const float* dist = (const float*)d_in[1];
    float* out = (float*)d_out;

    const int B = 4;
    const int H0 = 1080, W0 = 1920;
    const int H1 = 540,  W1 = 960;
    const int H2 = 270,  W2 = 480;

    char*  ws  = (char*)d_ws;
    size_t off = 0;
    auto alloc = [&](size_t bytes) -> void* {
        void* p = ws + off;
        off += (bytes + 255) & ~(size_t)255;
        return p;
    };
    float* gw    = (float*)alloc(34 * sizeof(float));   // weight table (17+9+5+3)
    float* ref1  = (float*)alloc((size_t)B * H1 * W1 * 4);
    float* dist1 = (float*)alloc((size_t)B * H1 * W1 * 4);
    float* ref2  = (float*)alloc((size_t)B * H2 * W2 * 4);
    float* dist2 = (float*)alloc((size_t)B * H2 * W2 * 4);

    // Stats grids (tile = tile_w(N) x 8), flattened y-major.
    // tile_w: 17->240 (1920 = 8*240 exact), 9->248.
    const int sx0 = (W0 + tile_w(17) - 1) / tile_w(17), sy0 = (H0 + 7) / 8;
    const int sx1 = (W1 + tile_w(9)  - 1) / tile_w(9),  sy1 = (H1 + 7) / 8;
    const int n0 = sx0 * sy0;      // 1080
    const int n1 = sx1 * sy1;      // 272
    const int n2 = 68;             // 34 y-tiles x 2 x-tiles (level2, tile_w(5)=252)
    const int n3 = 17;             // 17 y-tiles x 1 x-tile  (level3, tile_w(3)=252)

    // Down grids: 120x8 output tiles (W1/W2 are exact multiples of 120).
    const int dgx1 = W1 / 120, nD1 = dgx1 * ((H1 + 7) / 8);
    const int dgx2 = W2 / 120, nD2 = dgx2 * ((H2 + 7) / 8);

    double2* part = (double2*)alloc((size_t)B * (n0 + n1 + n2 + n3) * sizeof(double2));
    double2* p0 = part;
    double2* p1 = p0 + (size_t)B * n0;
    double2* p2 = p1 + (size_t)B * n1;
    double2* p3 = p2 + (size_t)B * n2;

    dim3 blk(256);

    // K0: weight table (once; bit-identical device float ops).
    init_weights_kernel<<<1, 64, 0, stream>>>(gw);

    // K1: stats<17>(level0) + down<9>(level0 -> level1)
    fused_kernel<17, 9><<<dim3(n0 + nD1, 1, B), blk, 0, stream>>>(
        ref, dist, gw, H0, W0, 128.0f, p0, sy0, sx0,
        ref1, dist1, H1, W1, dgx1, n0);

    // K2: stats<9>(level1) + down<5>(level1 -> level2)
    fused_kernel<9, 5><<<dim3(n1 + nD2, 1, B), blk, 0, stream>>>(
        ref1, dist1, gw, H1, W1, 0.0f, p1, sy1, sx1,
        ref2, dist2, H2, W2, dgx2, n1);

    // KL23: stats<5>(level2) ∥ stats<3>(level3 recomputed in-block).
    // Replaces old K3 (stats<5>+down<3>) and K4 (stats<3>) -- one less boundary.
    level23_kernel<<<dim3(n2 + n3, 1, B), blk, 0, stream>>>(
        ref2, dist2, gw, p2, p3);

    // K5: num/den per (b, scale)
    reduce_kernel<<<16, 256, 0, stream>>>(
        part, out,
        make_int4(0, B * n0, B * (n0 + n1), B * (n0 + n1 + n2)),
        make_int4(n0, n1, n2, n3));
}

// Round 12
// 164.376 us; speedup vs baseline: 1.1235x; 1.0126x over previous
//
#include <hip/hip_runtime.h>
#include <math.h>

#define VIF_EPS       1e-10f
#define SIGMA_NSQ     2.0f
#define SIGMA_MAX_INV (4.0f / (255.0f * 255.0f))
#define GAIN_LIMIT    100.0f

typedef float v2f __attribute__((ext_vector_type(2)));
typedef float v4f __attribute__((ext_vector_type(4)));

static __device__ __forceinline__ v2f splat2(float s) {
    v2f v; v.x = s; v.y = s; return v;
}

// jnp.pad mode='reflect' (no edge duplication). Overshoot < dim, single reflection suffices.
__device__ __forceinline__ int reflect_idx(int i, int n) {
    i = (i < 0) ? -i : i;
    i = (i >= n) ? (2 * n - 2 - i) : i;
    return i;
}

// Reference: sigma=N/5; g=exp(-x^2/(2 sigma^2)); win=outer(g,g)/sum -> separable gn = g/sum(g).
// R9: computed once into workspace (same device float ops -> bit-identical weights).
template <int N>
__device__ __forceinline__ void fill_weights_global(float* gw) {
    const float sigma = (float)N / 5.0f;
    const float denom = 2.0f * sigma * sigma;
    float tmp[N];
    float s = 0.0f;
    for (int i = 0; i < N; ++i) {
        float x = (float)i - (float)(N - 1) * 0.5f;
        float g = expf(-(x * x) / denom);
        tmp[i] = g;
        s += g;
    }
    for (int i = 0; i < N; ++i) gw[i] = tmp[i] / s;
}

__global__ __launch_bounds__(64) void init_weights_kernel(float* __restrict__ gw) {
    const int tid = threadIdx.x;
    if (tid == 0) fill_weights_global<17>(gw + 0);
    else if (tid == 1) fill_weights_global<9>(gw + 17);
    else if (tid == 2) fill_weights_global<5>(gw + 26);
    else if (tid == 3) fill_weights_global<3>(gw + 31);
}

// Weight buffer offsets per N.
__host__ __device__ constexpr int w_off(int N) {
    return (N == 17) ? 0 : (N == 9) ? 17 : (N == 5) ? 26 : 31;
}

// R7: 256-column tile. Output tile width (multiple of 4). 1920 = 8*240 exact.
constexpr int tile_w(int N) { return (256 - (N - 1)) & ~3; }

// ---- static shared layouts ----
// R8: EXACT-FIT 40960 B = 4 blocks/CU in 160 KiB exactly (stats path).
template <int N>
struct alignas(16) StatsSmem {
    v2f   a[8][256];    // (conv r, conv d)           16384 B
    v2f   bq[8][256];   // (conv r^2, conv d^2)       16384 B
    float c[8][256];    // conv rd                     8192 B
};                      // total 40960 B exactly
// R15: stats<3>-from-level2 working set (KL23 only; ~60 KB, occupancy moot there).
struct alignas(16) Stats3Smem {
    union {
        StatsSmem<3> planes;   // 40960 B (stats phases)
        v2f vb3[10][481];      // 38480 B (build phases A/B)
    } u2;
    v2f patch[10][240];        // 19200 B
};

// ---------------- stats body (vertical-first separable VIF) ----------------
// bx flattened Y-MAJOR (ytile = bx % sy) for L2 reuse of vertical halos.
// R6: channel-pair packed fp32. R7: 1 column/thread phase 1; halo-minimum rows.
// R8: exact-fit LDS + rsum overlay. R9: weights from global. R13: burst loads.
// R15: FROM_PATCH source (bit-identical, proven R8/R11). R16 (this round):
// DN>0 fuses the downsample INTO the stats tile. A stats<N> tile's loaded rows
// [y0-P, y0+P+7] x cols [x0-P, x0+255] contain every input of a (TW/2)x4 down
// tile at (x0/2, y0/2): row identity stats_i = 2t+OFF+j, col identity
// cc = 2xd'+OFF+jc with OFF = (N-1)/2-(DN-1)/2 -- same reflected indices, same
// shifted values, same j-ascending tap order as the old down_body ->
// bit-identical level outputs. Kills the down blocks' full re-read of the level.
template <int N, bool FROM_PATCH, int DN>
__device__ __forceinline__ void stats_body(
    StatsSmem<N>& sm, const float* __restrict__ refp, const float* __restrict__ distp,
    const v2f* __restrict__ patch,
    const float* __restrict__ gw, const float* __restrict__ gwd,
    float* __restrict__ drout, float* __restrict__ ddout, int dh2, int dw2,
    int h, int w, float shift, double2* __restrict__ partial,
    int sy, int sx, int bx, int b) {
    constexpr int P   = (N - 1) / 2;
    constexpr int TW  = tile_w(N);
    constexpr int TH  = 8;
    constexpr int LR  = TH + 2 * P;      // rows loaded per column (halo minimum)
    constexpr int XG4 = TW / 4;          // 4-output x-groups per row
    constexpr int NT  = TH * XG4;        // phase-2 tasks (<= 504)
    constexpr int REPS = (NT + 255) / 256;
    constexpr int OFF = (DN > 0) ? (N - 1) / 2 - (DN - 1) / 2 : 0;

    const int tid = threadIdx.x;
    const int ytile = bx % sy;
    const int xtile = bx / sy;
    const int x0 = xtile * TW;
    const int y0 = ytile * TH;

    float wr[N];
#pragma unroll
    for (int j = 0; j < N; ++j) wr[j] = gw[j];   // uniform -> s_load, stays SGPR

    float wd[DN > 0 ? DN : 1];
    if constexpr (DN > 0) {
#pragma unroll
        for (int j = 0; j < DN; ++j) wd[j] = gwd[j];
    }

    // Down vertical accumulators (4 decimated rows). +8 VGPR; live thru phase 2.
    v2f dacc[4];
    if constexpr (DN > 0) {
#pragma unroll
        for (int t = 0; t < 4; ++t) dacc[t] = splat2(0.f);
    }

    // ---- Phase 1: vertical conv (1 column/thread, 8 stats + 4 down outputs) ----
    {
        const int cc = tid;                       // column 0..255
        const int gx = reflect_idx(x0 + cc - P, w);

        v2f accA[TH], accB[TH];
        float accC[TH];
#pragma unroll
        for (int t = 0; t < TH; ++t) {
            accA[t] = splat2(0.f);
            accB[t] = splat2(0.f);
            accC[t] = 0.f;
        }

        auto acc_push = [&](int i, float r, float d) {
            v2f rd; rd.x = r; rd.y = d;
            v2f sq = rd * rd;          // v_pk_mul_f32: (r^2, d^2)
            float x = r * d;
#pragma unroll
            for (int t = 0; t < TH; ++t) {
                const int j = i - t;               // j-ascending per output t
                if (j >= 0 && j < N) {
                    const float wj = wr[j];
                    accA[t] += splat2(wj) * rd;    // v_pk_fma_f32
                    accB[t] += splat2(wj) * sq;
                    accC[t] += wj * x;
                }
            }
            if constexpr (DN > 0) {
#pragma unroll
                for (int t = 0; t < 4; ++t) {
                    const int j = i - 2 * t - OFF; // j-ascending (down tap order)
                    if (j >= 0 && j < DN) dacc[t] += splat2(wd[j]) * rd;
                }
            }
        };

        if constexpr (FROM_PATCH) {
            // R15: level-3 values recomputed in-block (reflection baked into rows).
#pragma unroll
            for (int i = 0; i < LR; ++i) {
                v2f pv = patch[i * 240 + gx];
                acc_push(i, pv.x, pv.y);
            }
        } else {
            const float* rbase = refp  + (size_t)b * h * w;   // uniform -> SGPR base
            const float* dbase = distp + (size_t)b * h * w;

            // R13: burst load (interior: shared u32 voffset walk; boundary: reflected).
            float rrow[LR], drow[LR];
            const int rowlo = y0 - P;
            if (rowlo >= 0 && rowlo + LR <= h) {
                unsigned voff = (unsigned)(rowlo * w + gx) * 4u;
                const unsigned vstep = (unsigned)w * 4u;
#pragma unroll
                for (int i = 0; i < LR; ++i) {
                    rrow[i] = *(const float*)((const char*)rbase + voff);
                    drow[i] = *(const float*)((const char*)dbase + voff);
                    voff += vstep;
                }
            } else {
#pragma unroll
                for (int i = 0; i < LR; ++i) {
                    const int gy = reflect_idx(rowlo + i, h);
                    const size_t o = (size_t)gy * w + gx;
                    rrow[i] = rbase[o];
                    drow[i] = dbase[o];
                }
            }
#pragma unroll
            for (int i = 0; i < LR; ++i)
                acc_push(i, rrow[i] - shift, drow[i] - shift);
        }
#pragma unroll
        for (int t = 0; t < TH; ++t) {
            sm.a[t][cc]  = accA[t];   // ds_write_b64, compile-time row offsets
            sm.bq[t][cc] = accB[t];
            sm.c[t][cc]  = accC[t];
        }
    }
    __syncthreads();

    // ---- Phase 2: horizontal conv + VIF math (4 outputs/task, REPS task reps) ----
    float num_v = 0.f, den_v = 0.f;
    {
        constexpr int WC  = N + 3;         // window columns (even: N odd)
        constexpr int F4C = (WC + 3) / 4;
#pragma unroll
        for (int rep = 0; rep < REPS; ++rep) {
            const int task = tid + 256 * rep;
            if (task < NT) {
                const int row = task / XG4;
                const int xg  = task - row * XG4;

                v2f muA[4], muB[4];
                float muC[4];
#pragma unroll
                for (int q = 0; q < 4; ++q) {
                    muA[q] = splat2(0.f);
                    muB[q] = splat2(0.f);
                    muC[q] = 0.f;
                }

                const v4f* A4 = (const v4f*)&sm.a[row][xg * 4];
                const v4f* B4 = (const v4f*)&sm.bq[row][xg * 4];
#pragma unroll
                for (int f = 0; f < WC / 2; ++f) {
                    v4f ta = A4[f];
                    v4f tb = B4[f];
#pragma unroll
                    for (int hlf = 0; hlf < 2; ++hlf) {
                        const int k = 2 * f + hlf;
                        v2f pa = hlf ? __builtin_shufflevector(ta, ta, 2, 3)
                                     : __builtin_shufflevector(ta, ta, 0, 1);
                        v2f pb = hlf ? __builtin_shufflevector(tb, tb, 2, 3)
                                     : __builtin_shufflevector(tb, tb, 0, 1);
#pragma unroll
                        for (int q = 0; q < 4; ++q) {
                            const int j = k - q;  // j-ascending per output
                            if (j >= 0 && j < N) {
                                const float wj = wr[j];
                                muA[q] += splat2(wj) * pa;
                                muB[q] += splat2(wj) * pb;
                            }
                        }
                    }
                }
                // Scalar rd plane.
                {
                    const v4f* C4 = (const v4f*)&sm.c[row][xg * 4];
#pragma unroll
                    for (int f = 0; f < F4C; ++f) {
                        v4f t = C4[f];
#pragma unroll
                        for (int e = 0; e < 4; ++e) {
                            const int k = 4 * f + e;
                            const float x = (e == 0) ? t.x : (e == 1) ? t.y
                                          : (e == 2) ? t.z : t.w;
#pragma unroll
                            for (int q = 0; q < 4; ++q) {
                                const int j = k - q;
                                if (j >= 0 && j < N) muC[q] += wr[j] * x;
                            }
                        }
                    }
                }

                const int gy = y0 + row;
#pragma unroll
                for (int q = 0; q < 4; ++q) {
                    int gx = x0 + xg * 4 + q;
                    if (gx < w && gy < h) {
                        float mu1 = muA[q].x, mu2 = muA[q].y;
                        float s1  = fmaxf(0.f, muB[q].x - mu1 * mu1);
                        float s2  = fmaxf(0.f, muB[q].y - mu2 * mu2);
                        float s12 = muC[q] - mu1 * mu2;

                        float g  = s12 / (s1 + VIF_EPS);
                        float sv = s2 - g * s12;
                        if (s1 < VIF_EPS) { g = 0.f; sv = s2; s1 = 0.f; }
                        if (s2 < VIF_EPS) { g = 0.f; sv = 0.f; }
                        if (g  < 0.f)     { sv = s2; g = 0.f; }
                        if (sv <= VIF_EPS) sv = VIF_EPS;
                        g = fminf(g, GAIN_LIMIT);

                        float num_ar = __log2f(1.f + g * g * s1 / (sv + SIGMA_NSQ));
                        float den_ar = __log2f(1.f + s1 / SIGMA_NSQ);
                        if (s12 < 0.f) num_ar = 0.f;
                        if (s1 < SIGMA_NSQ) { num_ar = 1.f - s2 * SIGMA_MAX_INV; den_ar = 1.f; }
                        num_v += num_ar;
                        den_v += den_ar;
                    }
                }
            }
        }
    }

    // Block reduction. rsum overlaid on the a-plane; down-vertical overlay on the
    // bq-plane (both dead after phase 2; all reads of both occur after barrier B).
#pragma unroll
    for (int off = 32; off > 0; off >>= 1) {
        num_v += __shfl_down(num_v, off);
        den_v += __shfl_down(den_v, off);
    }
    __syncthreads();                      // A: phase-2 LDS reads complete
    float* rs = reinterpret_cast<float*>(&sm);
    const int wid = tid >> 6, lane = tid & 63;
    if (lane == 0) { rs[wid] = num_v; rs[4 + wid] = den_v; }
    if constexpr (DN > 0) {
        v2f* vbd = &sm.bq[0][0];
#pragma unroll
        for (int t = 0; t < 4; ++t) vbd[t * 256 + tid] = dacc[t];   // ds_write_b64
    }
    __syncthreads();                      // B

    if constexpr (DN > 0) {
        // Horizontal decimate: (TW/2) x 4 down outputs; taps jc ascending over
        // vbd[row][2*xd' + OFF + jc] == old down_body window order.
        constexpr int XGD = TW / 8;                 // x-groups of 4 outputs
        if (tid < 4 * XGD) {
            const int row = tid / XGD;
            const int xg  = tid - row * XGD;
            const v2f* vrow = &sm.bq[0][0] + row * 256;
            v2f o[4];
#pragma unroll
            for (int q = 0; q < 4; ++q) o[q] = splat2(0.f);
#pragma unroll
            for (int jc = 0; jc < DN; ++jc) {
                const v2f wj = splat2(wd[jc]);
#pragma unroll
                for (int q = 0; q < 4; ++q)
                    o[q] += wj * vrow[8 * xg + 2 * q + OFF + jc];
            }
            const int gy2 = (y0 >> 1) + row;
            const int gx2 = (x0 >> 1) + 4 * xg;
            if (gy2 < dh2 && gx2 < dw2) {   // dims all %4==0 -> no float4 straddle
                float* rp = drout + (size_t)b * dh2 * dw2 + (size_t)gy2 * dw2 + gx2;
                float* dp = ddout + (size_t)b * dh2 * dw2 + (size_t)gy2 * dw2 + gx2;
                *(float4*)rp = make_float4(o[0].x, o[1].x, o[2].x, o[3].x);
                *(float4*)dp = make_float4(o[0].y, o[1].y, o[2].y, o[3].y);
            }
        }
    }
    if (tid == 0) {
        float ns = rs[0] + rs[1] + rs[2] + rs[3];
        float ds = rs[4] + rs[5] + rs[6] + rs[7];
        partial[(size_t)b * (sy * sx) + bx] = make_double2((double)ns, (double)ds);
    }
}

// ---------------- K1/K2: stats<NS> with fused down<ND> ----------------
template <int NS, int ND>
__global__ __launch_bounds__(256) void stats_down_kernel(
    const float* __restrict__ sref, const float* __restrict__ sdist,
    const float* __restrict__ gw,
    int sh, int sw, float sshift, double2* __restrict__ partial, int sy, int sx,
    float* __restrict__ drout, float* __restrict__ ddout, int dh2, int dw2) {
    __shared__ StatsSmem<NS> sm;
    stats_body<NS, false, ND>(sm, sref, sdist, nullptr,
                              gw + w_off(NS), gw + w_off(ND),
                              drout, ddout, dh2, dw2,
                              sh, sw, sshift, partial, sy, sx,
                              blockIdx.x, blockIdx.z);
}

// ---------------- R15: build level-3 patch in LDS from level2 ----------------
// Replicates down<3>'s exact float ops -> level3 bit-identical (proven R8/R11).
__device__ __forceinline__ void build_l3_patch(
    v2f* __restrict__ vb3 /*[10][481]*/, v2f* __restrict__ patch /*[10][240]*/,
    const float* __restrict__ r2, const float* __restrict__ d2,
    const float* __restrict__ gw3, int y0, int b) {
    constexpr int H2v = 270, W2v = 480, H3v = 135;
    const int tid = threadIdx.x;
    const float w0 = gw3[0], w1 = gw3[1], w2 = gw3[2];
    const float* rb = r2 + (size_t)b * H2v * W2v;
    const float* db = d2 + (size_t)b * H2v * W2v;

    // Phase A: vertical decimate. t -> level2 col reflect(t-1, 480).
#pragma unroll
    for (int rep = 0; rep < 2; ++rep) {
        const int t = tid + 256 * rep;
        if (t < 481) {
            const int c2 = reflect_idx(t - 1, W2v);
#pragma unroll
            for (int py = 0; py < 10; ++py) {
                const int y3  = reflect_idx(y0 - 1 + py, H3v);   // level3 reflection
                const int r0  = reflect_idx(2 * y3 - 1, H2v);    // level2 reflection
                const int r1  = 2 * y3;
                const int r2i = 2 * y3 + 1;                      // <= 269, in range
                v2f m = splat2(0.f);
                v2f x;
                x.x = rb[(size_t)r0 * W2v + c2];  x.y = db[(size_t)r0 * W2v + c2];
                m += splat2(w0) * x;
                x.x = rb[(size_t)r1 * W2v + c2];  x.y = db[(size_t)r1 * W2v + c2];
                m += splat2(w1) * x;
                x.x = rb[(size_t)r2i * W2v + c2]; x.y = db[(size_t)r2i * W2v + c2];
                m += splat2(w2) * x;
                vb3[py * 481 + t] = m;
            }
        }
    }
    __syncthreads();
    // Phase B: horizontal decimate -> patch[py][x3], tap j uses vb3[2*x3 + j].
#pragma unroll
    for (int rep = 0; rep < 10; ++rep) {
        const int idx = tid + 256 * rep;
        if (idx < 2400) {
            const int py = idx / 240;
            const int x3 = idx - py * 240;
            v2f o = splat2(0.f);
            o += splat2(w0) * vb3[py * 481 + 2 * x3 + 0];
            o += splat2(w1) * vb3[py * 481 + 2 * x3 + 1];
            o += splat2(w2) * vb3[py * 481 + 2 * x3 + 2];
            patch[py * 240 + x3] = o;
        }
    }
    __syncthreads();
}

// ---------------- KL23: stats<5>(level2) ∥ stats<3>(recomputed level3) ----------------
// Fence-free (R11): both halves depend only on level2; partials to K5 as before.
__global__ __launch_bounds__(256) void level23_kernel(
    const float* __restrict__ ref2, const float* __restrict__ dist2,
    const float* __restrict__ gw,
    double2* __restrict__ p2, double2* __restrict__ p3) {
    __shared__ union {
        StatsSmem<5> s5;
        Stats3Smem   s3;
    } u;
    const int bx = blockIdx.x;   // 0..84
    const int b  = blockIdx.z;

    if (bx < 68) {
        stats_body<5, false, 0>(u.s5, ref2, dist2, nullptr,
                                gw + w_off(5), nullptr,
                                nullptr, nullptr, 0, 0,
                                270, 480, 0.f, p2, 34, 2, bx, b);
    } else {
        const int bx3 = bx - 68;              // 0..16, sy3=17, sx3=1
        build_l3_patch(&u.s3.u2.vb3[0][0], &u.s3.patch[0][0],
                       ref2, dist2, gw + w_off(3), bx3 * 8, b);
        stats_body<3, true, 0>(u.s3.u2.planes, nullptr, nullptr, &u.s3.patch[0][0],
                               gw + w_off(3), nullptr,
                               nullptr, nullptr, 0, 0,
                               135, 240, 0.f, p3, 17, 1, bx3, b);
    }
}

// 16 blocks: one per (batch, scale). Sums double2 partials, writes num/den to out.
__global__ __launch_bounds__(256) void reduce_kernel(
    const double2* __restrict__ part, float* __restrict__ out,
    int4 bases, int4 counts) {
    __shared__ double sn[4], sd[4];
    const int s = blockIdx.x & 3;
    const int b = blockIdx.x >> 2;
    const int base = (&bases.x)[s];
    const int cnt  = (&counts.x)[s];
    const double2* p = part + base + (size_t)b * cnt;

    double ns = 0.0, ds = 0.0;
    for (int i = threadIdx.x; i < cnt; i += 256) {
        double2 v = p[i];
        ns += v.x;
        ds += v.y;
    }
#pragma unroll
    for (int off = 32; off > 0; off >>= 1) {
        ns += __shfl_down(ns, off);
        ds += __shfl_down(ds, off);
    }
    const int wid = threadIdx.x >> 6, lane = threadIdx.x & 63;
    if (lane == 0) { sn[wid] = ns; sd[wid] = ds; }
    __syncthreads();
    if (threadIdx.x == 0) {
        double Nv = sn[0] + sn[1] + sn[2] + sn[3];
        double Dv = sd[0] + sd[1] + sd[2] + sd[3];
        out[b * 4 + s] = (float)(Nv / Dv);
    }
}

extern "C" void kernel_launch(void* const* d_in, const int* in_sizes, int n_in,
                              void* d_out, int out_size, void* d_ws, size_t ws_size,
                              hipStream_t stream) {
    const float* ref  = (const float*)d_in[0];
    const float* dist = (const float*)d_in[1];
    float* out = (float*)d_out;

    const int B = 4;
    const int H0 = 1080, W0 = 1920;
    const int H1 = 540,  W1 = 960;
    const int H2 = 270,  W2 = 480;

    char*  ws  = (char*)d_ws;
    size_t off = 0;
    auto alloc = [&](size_t bytes) -> void* {
        void* p = ws + off;
        off += (bytes + 255) & ~(size_t)255;
        return p;
    };
    float* gw    = (float*)alloc(34 * sizeof(float));   // weight table (17+9+5+3)
    float* ref1  = (float*)alloc((size_t)B * H1 * W1 * 4);
    float* dist1 = (float*)alloc((size_t)B * H1 * W1 * 4);
    float* ref2  = (float*)alloc((size_t)B * H2 * W2 * 4);
    float* dist2 = (float*)alloc((size_t)B * H2 * W2 * 4);

    // Stats grids (tile = tile_w(N) x 8), flattened y-major.
    // tile_w: 17->240 (1920 = 8*240 exact), 9->248.
    const int sx0 = (W0 + tile_w(17) - 1) / tile_w(17), sy0 = (H0 + 7) / 8;
    const int sx1 = (W1 + tile_w(9)  - 1) / tile_w(9),  sy1 = (H1 + 7) / 8;
    const int n0 = sx0 * sy0;      // 1080
    const int n1 = sx1 * sy1;      // 272
    const int n2 = 68;             // 34 y-tiles x 2 x-tiles (level2)
    const int n3 = 17;             // 17 y-tiles x 1 x-tile  (level3)

    double2* part = (double2*)alloc((size_t)B * (n0 + n1 + n2 + n3) * sizeof(double2));
    double2* p0 = part;
    double2* p1 = p0 + (size_t)B * n0;
    double2* p2 = p1 + (size_t)B * n1;
    double2* p3 = p2 + (size_t)B * n2;

    dim3 blk(256);

    // K0: weight table (once; bit-identical device float ops).
    init_weights_kernel<<<1, 64, 0, stream>>>(gw);

    // K1: stats<17>(level0) with FUSED down<9> (level0 -> level1).
    // R16: per-tile containment -> down blocks eliminated (grid 1624->1080 per
    // batch), level0 read ONCE (FETCH ~132 -> ~75 MB).
    stats_down_kernel<17, 9><<<dim3(n0, 1, B), blk, 0, stream>>>(
        ref, dist, gw, H0, W0, 128.0f, p0, sy0, sx0,
        ref1, dist1, H1, W1);

    // K2: stats<9>(level1) with FUSED down<5> (level1 -> level2).
    stats_down_kernel<9, 5><<<dim3(n1, 1, B), blk, 0, stream>>>(
        ref1, dist1, gw, H1, W1, 0.0f, p1, sy1, sx1,
        ref2, dist2, H2, W2);

    // KL23: stats<5>(level2) ∥ stats<3>(level3 recomputed in-block).
    level23_kernel<<<dim3(n2 + n3, 1, B), blk, 0, stream>>>(
        ref2, dist2, gw, p2, p3);

    // K5: num/den per (b, scale)
    reduce_kernel<<<16, 256, 0, stream>>>(
        part, out,
        make_int4(0, B * n0, B * (n0 + n1), B * (n0 + n1 + n2)),
        make_int4(n0, n1, n2, n3));
}